// Round 14
// baseline (683.716 us; speedup 1.0000x reference)
//
#include <hip/hip_runtime.h>
#include <hip/hip_bf16.h>

// GCN (2-layer GCNConv + mean-pool + linear head + log_softmax) on MI355X.
// bf16 intermediates + MFMA GEMM (validated r13) + feature-panel-split agg
// (this round): 2 passes of 64 features halve the gather working set per pass
// (25.6 -> 12.8 MB) to raise the L2 hit rate on the fill-path-bound gather.
constexpr int N_ = 100000;   // nodes
constexpr int E_ = 3200000;  // edges
constexpr int HD = 128;      // feature dim (D == H == 128)
constexpr int G_ = 512;      // graphs
constexpr int C_ = 10;       // classes

constexpr int NB  = 782;     // buckets of 128 nodes: ceil(100000/128)
constexpr int CAP = 6144;    // staging slots per bucket (mean 4224, std ~65)
constexpr int ITEMS = E_ + N_;  // edges + self loops

typedef __bf16  bf16x8 __attribute__((ext_vector_type(8)));
typedef float   f32x4  __attribute__((ext_vector_type(4)));

// bf16 <-> f32 helpers (RNE round; values are finite).
__device__ __forceinline__ float b2f_lo(unsigned u) { return __uint_as_float(u << 16); }
__device__ __forceinline__ float b2f_hi(unsigned u) { return __uint_as_float(u & 0xFFFF0000u); }
__device__ __forceinline__ unsigned short f2b(float f) {
    unsigned u = __float_as_uint(f);
    u += 0x7FFFu + ((u >> 16) & 1u);
    return (unsigned short)(u >> 16);
}

// ---------------------------------------------------------------------------
// Bucketed CSR build (unchanged from r13's passing kernel).
// ---------------------------------------------------------------------------
__global__ __launch_bounds__(256) void k_scatter(const int* __restrict__ ei,
                                                 int* __restrict__ cursor,
                                                 unsigned int* __restrict__ staging) {
    __shared__ int lhist[NB];
    __shared__ int lbase[NB];
    const int t = threadIdx.x;
    const int per = (ITEMS + gridDim.x - 1) / gridDim.x;
    const int start = blockIdx.x * per;
    const int end = min(start + per, ITEMS);
    for (int b = t; b < NB; b += 256) lhist[b] = 0;
    __syncthreads();
    for (int i = start + t; i < end; i += 256) {
        int c = (i < E_) ? ei[E_ + i] : (i - E_);
        atomicAdd(&lhist[c >> 7], 1);
    }
    __syncthreads();
    for (int b = t; b < NB; b += 256) {
        int cnt = lhist[b];
        lbase[b] = (cnt > 0) ? atomicAdd(&cursor[b], cnt) : 0;
        lhist[b] = 0;  // reuse as local rank counter
    }
    __syncthreads();
    for (int i = start + t; i < end; i += 256) {
        int r, c;
        if (i < E_) { r = ei[i]; c = ei[E_ + i]; }
        else        { r = c = i - E_; }
        int b = c >> 7;
        int pos = lbase[b] + atomicAdd(&lhist[b], 1);
        if (pos < CAP)
            staging[(size_t)b * CAP + pos] =
                ((unsigned)(c & 127) << 17) | (unsigned)r;  // r < 2^17
    }
}

__global__ __launch_bounds__(1024) void k_scanb(const int* __restrict__ cursor,
                                                int* __restrict__ bstart,
                                                int* __restrict__ off) {
    __shared__ int s[1024];
    const int t = threadIdx.x;
    s[t] = (t < NB) ? cursor[t] : 0;
    __syncthreads();
    for (int d = 1; d < 1024; d <<= 1) {
        int v = (t >= d) ? s[t - d] : 0;
        __syncthreads();
        s[t] += v;
        __syncthreads();
    }
    if (t < NB) bstart[t] = s[t] - cursor[t];
    if (t == 0) { bstart[NB] = ITEMS; off[N_] = ITEMS; }
}

__global__ __launch_bounds__(256) void k_finalize(const unsigned int* __restrict__ staging,
                                                  const int* __restrict__ cursor,
                                                  const int* __restrict__ bstart,
                                                  int* __restrict__ off,
                                                  float* __restrict__ dinv,
                                                  int* __restrict__ src) {
    __shared__ int ldeg[128];
    __shared__ int loff[128];
    __shared__ int lcur[128];
    const int b = blockIdx.x;
    const int t = threadIdx.x;
    const int cnt = min(cursor[b], CAP);
    const int base = bstart[b];
    if (t < 128) ldeg[t] = 0;
    __syncthreads();
    for (int i = t; i < cnt; i += 256)
        atomicAdd(&ldeg[staging[(size_t)b * CAP + i] >> 17], 1);
    __syncthreads();
    if (t == 0) {
        int run = 0;
        for (int l = 0; l < 128; ++l) { loff[l] = run; run += ldeg[l]; }
    }
    __syncthreads();
    if (t < 128) {
        int node = b * 128 + t;
        if (node < N_) {
            off[node] = base + loff[t];
            dinv[node] = rsqrtf((float)ldeg[t]);  // deg >= 1 (self loop)
        }
        lcur[t] = loff[t];
    }
    __syncthreads();
    for (int i = t; i < cnt; i += 256) {
        unsigned item = staging[(size_t)b * CAP + i];
        int cl = item >> 17;
        int r = (int)(item & 0x1FFFFu);
        int pos = atomicAdd(&lcur[cl], 1);
        src[base + pos] = r;
    }
}

// ---------------------------------------------------------------------------
// W repack: fp32 [128][128] (k-major) -> bf16 B-fragment buffer (unchanged).
// ---------------------------------------------------------------------------
__global__ __launch_bounds__(256) void k_prepW(const float* __restrict__ W,
                                               unsigned short* __restrict__ wf) {
    const int s = blockIdx.x * 256 + threadIdx.x;  // 0..2047
    if (s >= 2048) return;
    const int ks   = s >> 9;
    const int rem  = s & 511;
    const int nt   = rem >> 6;
    const int lane = rem & 63;
    const int kb = ks * 32 + (lane >> 4) * 8;
    const int n  = nt * 16 + (lane & 15);
    unsigned short tmp[8];
#pragma unroll
    for (int i = 0; i < 8; ++i) tmp[i] = f2b(W[(size_t)(kb + i) * HD + n]);
    uint4 o;
    o.x = (unsigned)tmp[0] | ((unsigned)tmp[1] << 16);
    o.y = (unsigned)tmp[2] | ((unsigned)tmp[3] << 16);
    o.z = (unsigned)tmp[4] | ((unsigned)tmp[5] << 16);
    o.w = (unsigned)tmp[6] | ((unsigned)tmp[7] << 16);
    *reinterpret_cast<uint4*>(wf + (size_t)s * 8) = o;
}

// ---------------------------------------------------------------------------
// MFMA GEMM (unchanged from r13's passing kernel).
// ---------------------------------------------------------------------------
template <bool XBF16>
__global__ __launch_bounds__(256) void k_gemm_mfma(const void* __restrict__ Xv,
                                                   const unsigned short* __restrict__ wf,
                                                   const float* __restrict__ dinv,
                                                   unsigned short* __restrict__ Y,
                                                   int nrows) {
    const int t = threadIdx.x;
    const int wid = t >> 6;
    const int lane = t & 63;
    const int rowbase = blockIdx.x * 64 + wid * 16;
    const int arow = rowbase + (lane & 15);       // A-fragment row
    const int aoff = (lane >> 4) * 8;             // k sub-offset within k-step

    f32x4 acc[8];
#pragma unroll
    for (int nt = 0; nt < 8; ++nt) acc[nt] = f32x4{0.f, 0.f, 0.f, 0.f};

#pragma unroll
    for (int ks = 0; ks < 4; ++ks) {
        bf16x8 af;
        if constexpr (XBF16) {
            uint4 raw = make_uint4(0, 0, 0, 0);
            if (arow < nrows) {
                const unsigned short* X = (const unsigned short*)Xv;
                raw = *reinterpret_cast<const uint4*>(X + (size_t)arow * HD + ks * 32 + aoff);
            }
            af = __builtin_bit_cast(bf16x8, raw);
        } else {
            float4 v0 = make_float4(0.f, 0.f, 0.f, 0.f);
            float4 v1 = make_float4(0.f, 0.f, 0.f, 0.f);
            if (arow < nrows) {
                const float* X = (const float*)Xv;
                const float* p = X + (size_t)arow * HD + ks * 32 + aoff;
                v0 = *reinterpret_cast<const float4*>(p);
                v1 = *reinterpret_cast<const float4*>(p + 4);
            }
            af[0] = (__bf16)v0.x; af[1] = (__bf16)v0.y;
            af[2] = (__bf16)v0.z; af[3] = (__bf16)v0.w;
            af[4] = (__bf16)v1.x; af[5] = (__bf16)v1.y;
            af[6] = (__bf16)v1.z; af[7] = (__bf16)v1.w;
        }
#pragma unroll
        for (int nt = 0; nt < 8; ++nt) {
            uint4 braw = *reinterpret_cast<const uint4*>(
                wf + ((size_t)((ks * 8 + nt) * 64 + lane)) * 8);
            bf16x8 bf = __builtin_bit_cast(bf16x8, braw);
            acc[nt] = __builtin_amdgcn_mfma_f32_16x16x32_bf16(af, bf, acc[nt], 0, 0, 0);
        }
    }

    const int cbase = lane & 15;
    const int rgrp  = (lane >> 4) * 4;
#pragma unroll
    for (int reg = 0; reg < 4; ++reg) {
        const int orow = rowbase + rgrp + reg;
        if (orow < nrows) {
            const float s = dinv[orow];
#pragma unroll
            for (int nt = 0; nt < 8; ++nt)
                Y[(size_t)orow * HD + nt * 16 + cbase] = f2b(acc[nt][reg] * s);
        }
    }
}

// ---------------------------------------------------------------------------
// Panel aggregation: out[n][fo:fo+64] =
//   bf16( relu(dinv[n] * sum_{r in list(n)} xws[r][fo:fo+64] + bias[fo:..]) )
// One wave per node; 64-feature panel -> 128 B/row-panel; lanes 0-31 even
// edge, 32-63 odd edge (4 B = 2 bf16 per lane); 16 loads in flight (4 KB);
// fp32 accum. Working set per pass = 12.8 MB (vs 25.6 full) -> higher L2 hit.
// ---------------------------------------------------------------------------
__global__ __launch_bounds__(64) void k_agg_p(const unsigned short* __restrict__ xws,
                                              const int* __restrict__ off,
                                              const int* __restrict__ src,
                                              const float* __restrict__ dinv,
                                              const float* __restrict__ bias,
                                              unsigned short* __restrict__ out,
                                              int fo) {
    const int n = blockIdx.x;
    const int t = threadIdx.x;
    const int half = t >> 5;
    const int q = t & 31;
    __shared__ int sh[128];
    const int s0 = off[n];
    const int m = off[n + 1] - s0;
    const int foq = fo + q * 2;  // feature index of this lane's pair
    float2 a0 = make_float2(0.f, 0.f);
    float2 a1 = make_float2(0.f, 0.f);
    for (int basei = 0; basei < m; basei += 128) {
        const int chunk = min(128, m - basei);
        if (t < chunk) sh[t] = src[s0 + basei + t];
        if (t + 64 < chunk) sh[t + 64] = src[s0 + basei + t + 64];
        __syncthreads();
        const int fp = chunk >> 1;  // full pairs
        int k = 0;
        for (; k + 16 <= fp; k += 16) {
            unsigned v[16];
#pragma unroll
            for (int u = 0; u < 16; ++u) {
                int r = sh[2 * (k + u) + half];
                v[u] = *reinterpret_cast<const unsigned*>(xws + (size_t)r * HD + foq);
            }
#pragma unroll
            for (int u = 0; u < 16; ++u) {
                float2& a = (u & 1) ? a1 : a0;
                a.x += b2f_lo(v[u]); a.y += b2f_hi(v[u]);
            }
        }
        for (; k < fp; ++k) {
            int r = sh[2 * k + half];
            unsigned vv = *reinterpret_cast<const unsigned*>(xws + (size_t)r * HD + foq);
            a0.x += b2f_lo(vv); a0.y += b2f_hi(vv);
        }
        if ((chunk & 1) && half == 0) {
            int r = sh[chunk - 1];
            unsigned vv = *reinterpret_cast<const unsigned*>(xws + (size_t)r * HD + foq);
            a0.x += b2f_lo(vv); a0.y += b2f_hi(vv);
        }
        __syncthreads();
    }
    float2 acc = make_float2(a0.x + a1.x, a0.y + a1.y);
    acc.x += __shfl_xor(acc.x, 32, 64);
    acc.y += __shfl_xor(acc.y, 32, 64);
    if (half == 0) {
        const float dn = dinv[n];
        float2 bb = *reinterpret_cast<const float2*>(bias + foq);
        float r0 = fmaxf(acc.x * dn + bb.x, 0.f);
        float r1 = fmaxf(acc.y * dn + bb.y, 0.f);
        unsigned o = (unsigned)f2b(r0) | ((unsigned)f2b(r1) << 16);
        *reinterpret_cast<unsigned*>(out + (size_t)n * HD + foq) = o;
    }
}

// ---------------------------------------------------------------------------
// Mean pool over sorted batch (bf16 input, fp32 output/accum) — unchanged.
// ---------------------------------------------------------------------------
__global__ __launch_bounds__(64) void k_pool(const unsigned short* __restrict__ h,
                                             const int* __restrict__ batch,
                                             float* __restrict__ pooled) {
    const int g = blockIdx.x;
    const int t = threadIdx.x;
    const int half = t >> 5;
    const int q = t & 31;
    auto lb = [&](int key) {
        int lo = 0, hi = N_;
        while (lo < hi) {
            int mid = (lo + hi) >> 1;
            if (batch[mid] < key) lo = mid + 1; else hi = mid;
        }
        return lo;
    };
    const int lo = lb(g), hi = lb(g + 1);
    const int m = hi - lo;
    float4 a0 = make_float4(0.f, 0.f, 0.f, 0.f);
    float4 a1 = make_float4(0.f, 0.f, 0.f, 0.f);
    const int fp = m >> 1;
    int k = 0;
    for (; k + 4 <= fp; k += 4) {
        uint2 v[4];
#pragma unroll
        for (int u = 0; u < 4; ++u) {
            int rr = lo + 2 * (k + u) + half;
            v[u] = *reinterpret_cast<const uint2*>(h + (size_t)rr * HD + q * 4);
        }
#pragma unroll
        for (int u = 0; u < 4; ++u) {
            float4& a = (u & 1) ? a1 : a0;
            a.x += b2f_lo(v[u].x); a.y += b2f_hi(v[u].x);
            a.z += b2f_lo(v[u].y); a.w += b2f_hi(v[u].y);
        }
    }
    for (; k < fp; ++k) {
        int rr = lo + 2 * k + half;
        uint2 vv = *reinterpret_cast<const uint2*>(h + (size_t)rr * HD + q * 4);
        a0.x += b2f_lo(vv.x); a0.y += b2f_hi(vv.x);
        a0.z += b2f_lo(vv.y); a0.w += b2f_hi(vv.y);
    }
    if ((m & 1) && half == 0) {
        int rr = lo + m - 1;
        uint2 vv = *reinterpret_cast<const uint2*>(h + (size_t)rr * HD + q * 4);
        a0.x += b2f_lo(vv.x); a0.y += b2f_hi(vv.x);
        a0.z += b2f_lo(vv.y); a0.w += b2f_hi(vv.y);
    }
    float4 acc;
    acc.x = a0.x + a1.x; acc.y = a0.y + a1.y;
    acc.z = a0.z + a1.z; acc.w = a0.w + a1.w;
    acc.x += __shfl_xor(acc.x, 32, 64);
    acc.y += __shfl_xor(acc.y, 32, 64);
    acc.z += __shfl_xor(acc.z, 32, 64);
    acc.w += __shfl_xor(acc.w, 32, 64);
    if (half == 0) {
        const float inv = 1.0f / fmaxf((float)m, 1.0f);
        *reinterpret_cast<float4*>(pooled + (size_t)g * HD + q * 4) =
            make_float4(acc.x * inv, acc.y * inv, acc.z * inv, acc.w * inv);
    }
}

// ---------------------------------------------------------------------------
// Head: logits = pooled @ Wout + bout; out = log_softmax(logits) — unchanged.
// ---------------------------------------------------------------------------
__global__ __launch_bounds__(64) void k_head(const float* __restrict__ pooled,
                                             const float* __restrict__ Wout,
                                             const float* __restrict__ bout,
                                             float* __restrict__ out) {
    const int g = blockIdx.x;
    const int t = threadIdx.x;
    __shared__ float sp[HD];
    __shared__ float sl[C_];
    sp[t] = pooled[(size_t)g * HD + t];
    sp[t + 64] = pooled[(size_t)g * HD + t + 64];
    __syncthreads();
    if (t < C_) {
        float d = bout[t];
        for (int k = 0; k < HD; ++k) d += sp[k] * Wout[k * C_ + t];
        sl[t] = d;
    }
    __syncthreads();
    if (t == 0) {
        float mx = sl[0];
        for (int c = 1; c < C_; ++c) mx = fmaxf(mx, sl[c]);
        float se = 0.f;
        for (int c = 0; c < C_; ++c) se += expf(sl[c] - mx);
        float lse = logf(se);
        for (int c = 0; c < C_; ++c) out[(size_t)g * C_ + c] = sl[c] - mx - lse;
    }
}

// ---------------------------------------------------------------------------

extern "C" void kernel_launch(void* const* d_in, const int* in_sizes, int n_in,
                              void* d_out, int out_size, void* d_ws, size_t ws_size,
                              hipStream_t stream) {
    const float* x    = (const float*)d_in[0];
    const float* W1   = (const float*)d_in[1];
    const float* b1   = (const float*)d_in[2];
    const float* W2   = (const float*)d_in[3];
    const float* b2   = (const float*)d_in[4];
    const float* Wout = (const float*)d_in[5];
    const float* bout = (const float*)d_in[6];
    const int*   ei   = (const int*)d_in[7];
    const int*   batch= (const int*)d_in[8];
    float* out = (float*)d_out;

    size_t o = 0;
    auto carve = [&](size_t bytes) {
        void* p = (char*)d_ws + o;
        o += (bytes + 15) & ~size_t(15);
        return p;
    };
    int*   cursor = (int*)carve(NB * 4);
    int*   bstart = (int*)carve((NB + 1) * 4);
    int*   off    = (int*)carve((N_ + 1) * 4);
    float* dinv   = (float*)carve(N_ * 4);
    int*   src    = (int*)carve((size_t)ITEMS * 4);
    unsigned short* wf1 = (unsigned short*)carve(2048 * 16);  // 32 KB fragments
    unsigned short* wf2 = (unsigned short*)carve(2048 * 16);  // 32 KB fragments
    unsigned short* bufA = (unsigned short*)carve((size_t)N_ * HD * 2);  // 25.6 MB
    unsigned short* bufB = (unsigned short*)carve((size_t)N_ * HD * 2);  // 25.6 MB
    float* pooled = (float*)carve((size_t)G_ * HD * 4);
    // staging (782*6144*4 B = 19.2 MB) aliases bufA (25.6 MB, dead until GEMM).
    unsigned int* staging = (unsigned int*)bufA;

    hipMemsetAsync(cursor, 0, NB * sizeof(int), stream);
    k_prepW   <<<8, 256, 0, stream>>>(W1, wf1);
    k_prepW   <<<8, 256, 0, stream>>>(W2, wf2);
    k_scatter <<<512, 256, 0, stream>>>(ei, cursor, staging);
    k_scanb   <<<1, 1024, 0, stream>>>(cursor, bstart, off);
    k_finalize<<<NB, 256, 0, stream>>>(staging, cursor, bstart, off, dinv, src);

    const int gblk = (N_ + 63) / 64;  // 1563
    // Layer 1
    k_gemm_mfma<false><<<gblk, 256, 0, stream>>>(x, wf1, dinv, bufA, N_);
    k_agg_p<<<N_, 64, 0, stream>>>(bufA, off, src, dinv, b1, bufB, 0);
    k_agg_p<<<N_, 64, 0, stream>>>(bufA, off, src, dinv, b1, bufB, 64);
    // Layer 2
    k_gemm_mfma<true><<<gblk, 256, 0, stream>>>(bufB, wf2, dinv, bufA, N_);
    k_agg_p<<<N_, 64, 0, stream>>>(bufA, off, src, dinv, b2, bufB, 0);
    k_agg_p<<<N_, 64, 0, stream>>>(bufA, off, src, dinv, b2, bufB, 64);
    // Pool + head
    k_pool<<<G_, 64, 0, stream>>>(bufB, batch, pooled);
    k_head<<<G_, 64, 0, stream>>>(pooled, Wout, bout, out);
}